// Round 6
// baseline (3035.946 us; speedup 1.0000x reference)
//
#include <hip/hip_runtime.h>
#include <stdint.h>

#define N_POINTS   400000
#define WIDTH      64
#define M_SAMPLES  1000          // N_POINTS / 400
#define NBLK       64
#define NTHR       256
#define NW         (NTHR / 64)   // 4 waves per block
#define NTOT       (NBLK * NTHR) // 16384 threads, 1 wave/SIMD on 64 CUs
#define PPT        25            // ceil(400000 / 16384)
#define TAIL_GID   (N_POINTS - (PPT - 1) * NTOT)  // 6784: gid < this => k=24 valid
#define EPAD       8             // entry stride in u64 words = 64 B = ONE cache line
#define NENT       (NBLK * NW)   // 256 entries (one per wave) per region
#define NREG       128           // region rotation; reuse distance 128
#define SLOT_WORDS (NREG * NENT * EPAD)   // 262144 words = 2 MiB

// Entry (single 8-B word at the head of a PRIVATE 64-B line; ONE writer/line):
//   [63:32] dist f32 bits (non-negative -> monotone u32)
//   [26:19] tag = i & 255
//   [18:0]  N - idx (1..400000 < 2^19; ties -> lowest idx wins)
// Region r = (i-1) & 127. Tag safety: stale entries in a region are from
// i-128 whose tag differs in bit 7; region r is first used at i = r+1 whose
// tag r+1 != 0, so initial zeros never validate. Overwrite-before-gather is
// impossible: storing i+2 requires gathering i+1, which requires ALL waves
// stored i+1, which requires every block finished gathering i (protocol
// verified R3/R5: absmax 0). One-writer-per-line removes the write-write
// ownership serialization measured in R5 (3170 -> 2595 us).

__global__ void fps_init(unsigned long long* slot, int* out) {
    int t = blockIdx.x * blockDim.x + threadIdx.x;
    if (t < SLOT_WORDS) slot[t] = 0ull;
    if (t == 0) out[0] = 0;      // seed index
}

// u64 max-reduce across 64 lanes via DPP row-scan, broadcast via readlane(63).
// bound_ctrl=false => out-of-row lanes keep old value (max no-op).
// (HW-verified on gfx950 in rounds 1/3/4/5.)
__device__ inline unsigned long long wave_max_u64(unsigned long long key) {
    unsigned int lo = (unsigned int)key;
    unsigned int hi = (unsigned int)(key >> 32);
#define FPS_DPP_STAGE(CTRL)                                                     \
    {                                                                           \
        unsigned int nlo = (unsigned int)__builtin_amdgcn_update_dpp(           \
            (int)lo, (int)lo, CTRL, 0xf, 0xf, false);                           \
        unsigned int nhi = (unsigned int)__builtin_amdgcn_update_dpp(           \
            (int)hi, (int)hi, CTRL, 0xf, 0xf, false);                           \
        unsigned long long cand = ((unsigned long long)nhi << 32) | nlo;        \
        unsigned long long cur  = ((unsigned long long)hi  << 32) | lo;         \
        if (cand > cur) { lo = nlo; hi = nhi; }                                 \
    }
    FPS_DPP_STAGE(0x111)  // row_shr:1
    FPS_DPP_STAGE(0x112)  // row_shr:2
    FPS_DPP_STAGE(0x114)  // row_shr:4
    FPS_DPP_STAGE(0x118)  // row_shr:8   -> lane15 of each row = row max
    FPS_DPP_STAGE(0x142)  // row_bcast15 -> lane31/63 = pair max
    FPS_DPP_STAGE(0x143)  // row_bcast31 -> lane63 = wave max
#undef FPS_DPP_STAGE
    unsigned int rlo = (unsigned int)__builtin_amdgcn_readlane((int)lo, 63);
    unsigned int rhi = (unsigned int)__builtin_amdgcn_readlane((int)hi, 63);
    return ((unsigned long long)rhi << 32) | rlo;
}

// Workspace requirement: SLOT_WORDS * 8 B = 2,097,152 B in d_ws.
__global__ __launch_bounds__(NTHR)
void fps_main(const float* __restrict__ feats, int* __restrict__ out,
              unsigned long long* __restrict__ slot)
{
    const int tid  = threadIdx.x;
    const int bid  = blockIdx.x;
    const int lane = tid & 63;
    const int wid  = tid >> 6;
    const int gid  = bid * NTHR + tid;

    // Register-resident points + running min squared distance
    float px[PPT], py[PPT], pz[PPT], dd[PPT];
#pragma unroll
    for (int k = 0; k < PPT; k++) {
        int j = gid + k * NTOT;
        if (j < N_POINTS) {
            // row start is 256-B aligned -> one dwordx4 gets x,y,z(,w)
            float4 v = *reinterpret_cast<const float4*>(feats + (size_t)j * WIDTH);
            px[k] = v.x; py[k] = v.y; pz[k] = v.z;
        } else {
            px[k] = 0.f; py[k] = 0.f; pz[k] = 0.f;
        }
        dd[k] = 1e10f;          // matches jnp.full(..., 1e10, f32)
    }

    __shared__ float s_qx, s_qy, s_qz;

    // Iteration-1 pivot = point 0 (bit-identical source values)
    float qx = feats[0];
    float qy = feats[1];
    float qz = feats[2];

    for (int i = 1; i < M_SAMPLES; i++) {
        const unsigned long long tg = (unsigned long long)(i & 255);
        unsigned long long* cur = slot + (size_t)((i - 1) & (NREG - 1)) * NENT * EPAD;

        // ---- compute pass: update dd, float-track per-thread best (dist,idx) ----
        float bd = -1.0f;
        unsigned int bj = 0;
#pragma unroll
        for (int k = 0; k < PPT; k++) {
            int j = gid + k * NTOT;
            // IEEE ops in reference order; _rn intrinsics block fp-contract
            float dx = __fsub_rn(px[k], qx);
            float dy = __fsub_rn(py[k], qy);
            float dz = __fsub_rn(pz[k], qz);
            float d  = __fadd_rn(__fadd_rn(__fmul_rn(dx, dx), __fmul_rn(dy, dy)),
                                 __fmul_rn(dz, dz));
            float nd = fminf(dd[k], d);
            dd[k] = nd;
            // strict > keeps the smallest j on ties (j ascends with k)
            bool upd = (nd > bd);
            if (k == PPT - 1) upd = upd && (gid < TAIL_GID);
            bd = upd ? nd : bd;
            bj = upd ? (unsigned int)j : bj;
        }
        unsigned long long key =
            ((unsigned long long)__float_as_uint(bd) << 32) |
            (tg << 19) |
            (unsigned long long)(N_POINTS - bj);

        // ---- per-wave DPP reduce + IMMEDIATE store to this wave's private
        //      cache line (no LDS staging, no pre-store barrier) ----
        unsigned long long wmax = wave_max_u64(key);
        if (lane == 0)
            __hip_atomic_store(&cur[(size_t)(bid * NW + wid) * EPAD], wmax,
                               __ATOMIC_RELAXED, __HIP_MEMORY_SCOPE_AGENT);

        if (wid == 0) {
            // ---- poll: lane l owns block l's 4 wave entries (4 private lines,
            //      loads issue back-to-back -> detect period ~ one load latency)
            const unsigned long long* pb = cur + (size_t)lane * NW * EPAD;
            unsigned long long k0 = 0, k1 = 0, k2 = 0, k3 = 0;
            bool ok0 = false, ok1 = false, ok2 = false, ok3 = false;
#define FPS_POLL(E)                                                              \
            if (!ok##E) {                                                        \
                unsigned long long w = __hip_atomic_load(pb + E * EPAD,          \
                    __ATOMIC_RELAXED, __HIP_MEMORY_SCOPE_AGENT);                 \
                if (((w >> 19) & 255ull) == tg) { k##E = w; ok##E = true; }      \
            }
            do {
                FPS_POLL(0) FPS_POLL(1) FPS_POLL(2) FPS_POLL(3)
            } while (!(ok0 & ok1 & ok2 & ok3));
#undef FPS_POLL

            // local max of this lane's 4 entries
            unsigned long long v = k0;
            if (k1 > v) v = k1;
            if (k2 > v) v = k2;
            if (k3 > v) v = k3;

            // ---- speculative pivot fetch: each lane loads ITS local-max
            //      candidate's row; latency overlaps the final DPP reduce ----
            unsigned int widx = N_POINTS - (unsigned int)(v & 0x7FFFFull);
            float4 pv = *reinterpret_cast<const float4*>(feats + (size_t)widx * WIDTH);

            unsigned long long win = wave_max_u64(v);

            // Exactly one lane matches (entry indices are globally distinct)
            if (v == win) {
                s_qx = pv.x; s_qy = pv.y; s_qz = pv.z;
                if (bid == 0) out[i] = (int)widx;
            }
        }
        // Single barrier: waves 1-3 arrive right after their store; wave 0
        // releases it once s_q* is written.
        __syncthreads();
        qx = s_qx; qy = s_qy; qz = s_qz;
    }
}

extern "C" void kernel_launch(void* const* d_in, const int* in_sizes, int n_in,
                              void* d_out, int out_size, void* d_ws, size_t ws_size,
                              hipStream_t stream) {
    const float* feats = (const float*)d_in[0];
    int* out = (int*)d_out;
    unsigned long long* slot = (unsigned long long*)d_ws;  // 2 MiB used

    fps_init<<<(SLOT_WORDS + 255) / 256, 256, 0, stream>>>(slot, out);
    // 64 blocks x 256 thr: 1 block/CU on 64 CUs, 1 wave/SIMD
    fps_main<<<NBLK, NTHR, 0, stream>>>(feats, out, slot);
}

// Round 7
// 2241.113 us; speedup vs baseline: 1.3547x; 1.3547x over previous
//
#include <hip/hip_runtime.h>
#include <stdint.h>

#define N_POINTS   400000
#define WIDTH      64
#define M_SAMPLES  1000          // N_POINTS / 400
#define NBLK       64
#define NTHR       512
#define NWAVE      (NTHR / 64)   // 8 waves per block
#define NTOT       (NBLK * NTHR) // 32768 threads -> 2 waves/SIMD on 64 CUs
#define PPT        13            // ceil(400000 / 32768)
#define TAIL_GID   (N_POINTS - (PPT - 1) * NTOT)  // 6784: gid < this => k=12 valid
#define EPAD       8             // entry stride = 64 B = ONE cache line, ONE writer
#define NREG       128           // region rotation; reuse distance 128
#define SLOT_WORDS (NREG * NBLK * EPAD)   // 65536 words = 512 KiB

// Entry (single 8-B word at the head of a PRIVATE 64-B line; ONE writer/line):
//   [63:32] dist f32 bits (non-negative -> monotone u32)
//   [26:19] tag = i & 255
//   [18:0]  N - idx (1..400000 < 2^19; ties -> lowest idx wins)
// Region r = (i-1) & 127. Stale entries are from i-128 whose 8-bit tag differs
// in bit 7; region r is first used at i = r+1 (tag != 0) so initial zeros never
// validate. Overwrite-before-gather impossible: storing iteration i+128's entry
// requires having gathered i+127, hence ALL blocks stored i+127, hence every
// block long since consumed region r at iteration i. (Tag protocol verified
// R6; one-writer-per-line verified R5: 3170 -> 2595 us; narrow funnel (block
// reduce, few visibility events) verified R5-vs-R6: 2595 vs 2928 us.)

__global__ void fps_init(unsigned long long* slot, int* out) {
    int t = blockIdx.x * blockDim.x + threadIdx.x;
    if (t < SLOT_WORDS) slot[t] = 0ull;
    if (t == 0) out[0] = 0;      // seed index
}

// u64 max-reduce via DPP row-scan (HW-verified rounds 1/3/4/5/6).
// STAGES=3 + SRC=7  : max over lanes 0..7   (block-level, 8 wave maxima)
// STAGES=6 + SRC=63 : max over all 64 lanes
template <int STAGES, int SRCLANE>
__device__ inline unsigned long long wave_scan_max_u64(unsigned long long key) {
    unsigned int lo = (unsigned int)key;
    unsigned int hi = (unsigned int)(key >> 32);
#define FPS_DPP_STAGE(CTRL)                                                     \
    {                                                                           \
        unsigned int nlo = (unsigned int)__builtin_amdgcn_update_dpp(           \
            (int)lo, (int)lo, CTRL, 0xf, 0xf, false);                           \
        unsigned int nhi = (unsigned int)__builtin_amdgcn_update_dpp(           \
            (int)hi, (int)hi, CTRL, 0xf, 0xf, false);                           \
        unsigned long long cand = ((unsigned long long)nhi << 32) | nlo;        \
        unsigned long long cur  = ((unsigned long long)hi  << 32) | lo;         \
        if (cand > cur) { lo = nlo; hi = nhi; }                                 \
    }
    if constexpr (STAGES > 0) FPS_DPP_STAGE(0x111)  // row_shr:1
    if constexpr (STAGES > 1) FPS_DPP_STAGE(0x112)  // row_shr:2
    if constexpr (STAGES > 2) FPS_DPP_STAGE(0x114)  // row_shr:4
    if constexpr (STAGES > 3) FPS_DPP_STAGE(0x118)  // row_shr:8
    if constexpr (STAGES > 4) FPS_DPP_STAGE(0x142)  // row_bcast15
    if constexpr (STAGES > 5) FPS_DPP_STAGE(0x143)  // row_bcast31
#undef FPS_DPP_STAGE
    unsigned int rlo = (unsigned int)__builtin_amdgcn_readlane((int)lo, SRCLANE);
    unsigned int rhi = (unsigned int)__builtin_amdgcn_readlane((int)hi, SRCLANE);
    return ((unsigned long long)rhi << 32) | rlo;
}

// Workspace requirement: SLOT_WORDS * 8 B = 524,288 B in d_ws.
__global__ __launch_bounds__(NTHR)
void fps_main(const float* __restrict__ feats, int* __restrict__ out,
              unsigned long long* __restrict__ slot)
{
    const int tid  = threadIdx.x;
    const int bid  = blockIdx.x;
    const int lane = tid & 63;
    const int wid  = tid >> 6;
    const int gid  = bid * NTHR + tid;

    // Register-resident points + running min squared distance (13x4 = 52 VGPR)
    float px[PPT], py[PPT], pz[PPT], dd[PPT];
#pragma unroll
    for (int k = 0; k < PPT; k++) {
        int j = gid + k * NTOT;
        if (j < N_POINTS) {
            // row start is 256-B aligned -> one dwordx4 gets x,y,z(,w)
            float4 v = *reinterpret_cast<const float4*>(feats + (size_t)j * WIDTH);
            px[k] = v.x; py[k] = v.y; pz[k] = v.z;
        } else {
            px[k] = 0.f; py[k] = 0.f; pz[k] = 0.f;
        }
        dd[k] = 1e10f;          // matches jnp.full(..., 1e10, f32)
    }

    __shared__ unsigned long long s_wmax[NWAVE];
    __shared__ float s_qx, s_qy, s_qz;

    // Iteration-1 pivot = point 0 (bit-identical source values)
    float qx = feats[0];
    float qy = feats[1];
    float qz = feats[2];

    for (int i = 1; i < M_SAMPLES; i++) {
        const unsigned long long tg = (unsigned long long)(i & 255);
        unsigned long long* cur = slot + (size_t)((i - 1) & (NREG - 1)) * NBLK * EPAD;

        // ---- compute pass: update dd, float-track per-thread best (dist,idx) ----
        float bd = -1.0f;
        unsigned int bj = 0;
#pragma unroll
        for (int k = 0; k < PPT; k++) {
            int j = gid + k * NTOT;
            // IEEE ops in reference order; _rn intrinsics block fp-contract
            float dx = __fsub_rn(px[k], qx);
            float dy = __fsub_rn(py[k], qy);
            float dz = __fsub_rn(pz[k], qz);
            float d  = __fadd_rn(__fadd_rn(__fmul_rn(dx, dx), __fmul_rn(dy, dy)),
                                 __fmul_rn(dz, dz));
            float nd = fminf(dd[k], d);
            dd[k] = nd;
            // strict > keeps the smallest j on ties (j ascends with k)
            bool upd = (nd > bd);
            if (k == PPT - 1) upd = upd && (gid < TAIL_GID);
            bd = upd ? nd : bd;
            bj = upd ? (unsigned int)j : bj;
        }
        unsigned long long key =
            ((unsigned long long)__float_as_uint(bd) << 32) |
            (tg << 19) |
            (unsigned long long)(N_POINTS - bj);

        // ---- per-wave DPP reduce, stage into LDS ----
        unsigned long long wmax = wave_scan_max_u64<6, 63>(key);
        if (lane == 0) s_wmax[wid] = wmax;
        __syncthreads();

        if (wid == 0) {
            // ---- block reduce: 8 wave maxima -> ONE store to a private line ----
            unsigned long long bk = (lane < NWAVE) ? s_wmax[lane] : 0ull;
            unsigned long long blockmax = wave_scan_max_u64<3, 7>(bk);
            if (lane == 0)
                __hip_atomic_store(&cur[(size_t)bid * EPAD], blockmax,
                                   __ATOMIC_RELAXED, __HIP_MEMORY_SCOPE_AGENT);

            // ---- poll: lane l waits on block l's entry (64 entries, exactly
            //      one private line per lane; per-lane tight retry loop) ----
            unsigned long long e;
            do {
                e = __hip_atomic_load(&cur[(size_t)lane * EPAD],
                                      __ATOMIC_RELAXED, __HIP_MEMORY_SCOPE_AGENT);
            } while (((e >> 19) & 255ull) != tg);

            // ---- speculative pivot fetch: each lane loads ITS candidate's
            //      row; latency overlaps the final DPP reduce ----
            unsigned int widx = N_POINTS - (unsigned int)(e & 0x7FFFFull);
            float4 pv = *reinterpret_cast<const float4*>(feats + (size_t)widx * WIDTH);

            unsigned long long win = wave_scan_max_u64<6, 63>(e);

            // Exactly one lane matches (entry indices are globally distinct)
            if (e == win) {
                s_qx = pv.x; s_qy = pv.y; s_qz = pv.z;
                if (bid == 0) out[i] = (int)widx;
            }
        }
        // Waves 1..7 wait here while wave 0 runs the exchange
        __syncthreads();
        qx = s_qx; qy = s_qy; qz = s_qz;
    }
}

extern "C" void kernel_launch(void* const* d_in, const int* in_sizes, int n_in,
                              void* d_out, int out_size, void* d_ws, size_t ws_size,
                              hipStream_t stream) {
    const float* feats = (const float*)d_in[0];
    int* out = (int*)d_out;
    unsigned long long* slot = (unsigned long long*)d_ws;  // 512 KiB used

    fps_init<<<(SLOT_WORDS + 255) / 256, 256, 0, stream>>>(slot, out);
    // 64 blocks x 512 thr: all blocks trivially co-resident
    fps_main<<<NBLK, NTHR, 0, stream>>>(feats, out, slot);
}